// Round 15
// baseline (171.661 us; speedup 1.0000x reference)
//
#include <hip/hip_runtime.h>
#include <math.h>

// Problem constants
#define BATCH 256
#define IC    1152   // 32*6*6 input capsule positions
#define DD    8
#define OO    10
#define EE    16
#define BTILE 64     // batches per block (wave w owns rows 16w..16w+15)
#define NBT   4      // BATCH / BTILE
#define NT    256    // 4 waves
#define CHUNK 4      // ijk per block -> LDS 28.7 KB -> 5 blocks/CU by LDS
#define NCHUNK 288   // IC / CHUNK -> grid 1152 = 4.5 blocks/CU
#define WPC   1280   // OO*DD*EE floats of W per ijk
#define WHALF ((size_t)IC * 160 * 8)      // shorts per W half-buffer

typedef __attribute__((ext_vector_type(8))) short short8;  // 8 bf16 (4 VGPR)
typedef __attribute__((ext_vector_type(4))) float f32x4;   // MFMA C/D

__device__ __forceinline__ unsigned short f2bf(float f) {  // RNE fp32->bf16
    unsigned u = __float_as_uint(f);
    unsigned r = u + 0x7FFFu + ((u >> 16) & 1u);
    return (unsigned short)(r >> 16);
}
__device__ __forceinline__ float bf2f(unsigned short h) {
    return __uint_as_float(((unsigned)h) << 16);
}

// prep: convert W fp32 -> bf16 hi/lo ONCE into the MFMA feed layout
// [ijk][o*16+e][d]. Verified bit-compatible r12/r13.
__global__ __launch_bounds__(256) void caps_prep_kernel(
    const float* __restrict__ W,            // [1152][10][8][16]
    unsigned short* __restrict__ w_hi,
    unsigned short* __restrict__ w_lo)
{
    const int idx = blockIdx.x * 256 + threadIdx.x;   // < 184320 = 1152*160
    const int ijk = idx / 160;
    const int oe  = idx - ijk * 160;
    const int o = oe >> 4, e = oe & 15;
    const float* src = W + (size_t)ijk * WPC + o * 128 + e;   // stride 16 over d
    short8 hv, lv;
    #pragma unroll
    for (int d = 0; d < 8; ++d) {
        const float f = src[d * 16];
        const unsigned short h = f2bf(f);
        hv[d] = (short)h;
        lv[d] = (short)f2bf(f - bf2f(h));
    }
    *reinterpret_cast<short8*>(w_hi + (size_t)idx * 8) = hv;
    *reinterpret_cast<short8*>(w_lo + (size_t)idx * 8) = lv;
}

// MFMA pass kernel. r15 = r13 structure with two occupancy levers:
//  - TWO-SWEEP routing (r12-proven-correct): sweep1 computes elg[10] with u
//    TRANSIENT (dies after its dot); sweep2 re-reads W via an opaque pointer
//    (defeats CSE) and recomputes u into sacc. Live set drops from
//    u40+vreg40+sacc40 (~150 -> 3 waves/SIMD tier) to sacc40+vreg40+elg10
//    (~115 -> 4 waves/SIMD tier, m69 boundary at 128). NO launch_bounds cap
//    (every capped build r1-r12 spilled; uncapped never did).
//  - CHUNK=4: LDS 28.7 KB -> 4+ blocks/CU by LDS; grid 1152 -> 4 blocks/CU
//    co-resident = 16 waves/CU (vs r13's 12).
//  - fold = __shfl_xor (r14's permlane asm was numerically WRONG; reverted).
//  MFMA packing (r10/r12 HW-verified): lane-group q supplies k=8q..8q+7;
//  A={Wh,Wl,Wh,0}[q], B={Xh,Xh,Xl,0}[q]; D: col=lane&15=b, row=4q+reg=e.
//  Checks: VGPR<=128 (go/no-go), WRITE_SIZE ~47.4 MB/pass (s_part only).
__global__ __launch_bounds__(NT) void caps_pass_kernel(
    const float* __restrict__ x,            // [256][1152][8]
    const unsigned short* __restrict__ w_hi,
    const unsigned short* __restrict__ w_lo,
    const float* __restrict__ V,            // [256][10][16]
    float* __restrict__ s_part,             // [NCHUNK][256][10][16]
    int first)
{
    __shared__ unsigned short wl_hi[CHUNK * 160 * 8];   // 10 KB
    __shared__ unsigned short wl_lo[CHUNK * 160 * 8];   // 10 KB
    __shared__ unsigned short x_hi[CHUNK][BTILE][8];    // 4 KB
    __shared__ unsigned short x_lo[CHUNK][BTILE][8];    // 4 KB
    __shared__ unsigned short zpad[8];                  // 16 B

    const int tid  = threadIdx.x;
    const int wv   = tid >> 6;
    const int lane = tid & 63;
    const int q    = lane >> 4;    // k-group (0..3)
    const int em   = lane & 15;    // A-row (e) / B-col (b-local)
    const int ijk0 = blockIdx.x * CHUNK;
    const int bg0  = blockIdx.y * BTILE;

    if (tid < 8) zpad[tid] = 0;

    // ---- stage W chunk: pure linear float4 copy from prepped global ----
    {
        const float4* sh = reinterpret_cast<const float4*>(w_hi + (size_t)ijk0 * 160 * 8);
        const float4* sl = reinterpret_cast<const float4*>(w_lo + (size_t)ijk0 * 160 * 8);
        float4* dh = reinterpret_cast<float4*>(wl_hi);
        float4* dl = reinterpret_cast<float4*>(wl_lo);
        #pragma unroll
        for (int i = 0; i < 3; ++i) {           // 3*256 >= 640 units
            const int f = tid + i * NT;
            if (f < CHUNK * 160) { dh[f] = sh[f]; dl[f] = sl[f]; }
        }
    }
    // ---- stage x chunk -> bf16 hi/lo, layout [s][b][d] (r10-verified) ----
    {
        const int b = tid >> 2, s = tid & 3;    // 256 units exactly, s fastest
        const float* xp = x + ((size_t)(bg0 + b) * IC + (ijk0 + s)) * DD;
        const float4 xa = *reinterpret_cast<const float4*>(xp);
        const float4 xb = *reinterpret_cast<const float4*>(xp + 4);
        const float vv[8] = {xa.x,xa.y,xa.z,xa.w, xb.x,xb.y,xb.z,xb.w};
        short8 hv, lv;
        #pragma unroll
        for (int j = 0; j < 8; ++j) {
            const unsigned short h = f2bf(vv[j]);
            hv[j] = (short)h;
            lv[j] = (short)f2bf(vv[j] - bf2f(h));
        }
        *reinterpret_cast<short8*>(&x_hi[s][b][0]) = hv;
        *reinterpret_cast<short8*>(&x_lo[s][b][0]) = lv;
    }

    // hoist v[b, o, e=4q..4q+3] into 10 float4 regs (routing passes only)
    f32x4 vreg[OO];
    const int b = bg0 + 16 * wv + em;
    if (!first) {
        #pragma unroll
        for (int o = 0; o < OO; ++o) {
            const float4 t = *reinterpret_cast<const float4*>(
                V + (size_t)b * (OO * EE) + o * EE + 4 * q);
            vreg[o] = (f32x4){t.x, t.y, t.z, t.w};
        }
    }
    __syncthreads();

    // per-lane operand bases (r10-verified packing):
    //   A(W): q0,q2 -> hi, q1 -> lo, q3 -> zpad
    //   B(X): q0,q1 -> hi, q2 -> lo, q3 -> zpad
    const unsigned short* wbase = (q == 1) ? wl_lo : ((q == 3) ? zpad : wl_hi);
    const unsigned short* xbase = (q == 2) ? &x_lo[0][0][0]
                                : ((q == 3) ? zpad : &x_hi[0][0][0]);
    const int msk = (q == 3) ? 0 : 1;

    // opaque copy of wbase for sweep 2: defeats ds_read CSE so sweep-1 u's
    // are NOT kept alive across the softmax (r12-proven-correct trick).
    uintptr_t wb2i = (uintptr_t)wbase;
    asm volatile("" : "+v"(wb2i));
    const unsigned short* wbase2 = (const unsigned short*)wb2i;

    f32x4 sacc[OO];
    #pragma unroll
    for (int o = 0; o < OO; ++o) sacc[o] = (f32x4){0.f, 0.f, 0.f, 0.f};

    #pragma unroll 1
    for (int s = 0; s < CHUNK; ++s) {
        const short8 xf = *reinterpret_cast<const short8*>(
            xbase + msk * ((s * BTILE + 16 * wv + em) * 8));
        const int woff = (s * 160 + em) * 8;

        if (!first) {
            // sweep 1: logits only; u transient (register diet)
            float elg[OO];
            #pragma unroll
            for (int o = 0; o < OO; ++o) {
                const short8 wf = *reinterpret_cast<const short8*>(
                    wbase + msk * (woff + o * 128));
                const f32x4 u = __builtin_amdgcn_mfma_f32_16x16x32_bf16(
                                    wf, xf, (f32x4){0.f,0.f,0.f,0.f}, 0, 0, 0);
                float t = u[0]*vreg[o][0] + u[1]*vreg[o][1]
                        + u[2]*vreg[o][2] + u[3]*vreg[o][3];
                t += __shfl_xor(t, 16);     // fold q-groups: full sum over e
                t += __shfl_xor(t, 32);
                elg[o] = __expf(t);         // bounded logits (r1-r13)
            }
            const float d01 = elg[0] + elg[1], d23 = elg[2] + elg[3];
            const float d45 = elg[4] + elg[5], d67 = elg[6] + elg[7];
            const float den = ((d01 + d23) + (d45 + d67)) + (elg[8] + elg[9]);
            const float rden = __fdividef(1.0f, den);
            // sweep 2: recompute u (opaque base), accumulate
            #pragma unroll
            for (int o = 0; o < OO; ++o) {
                const short8 wf = *reinterpret_cast<const short8*>(
                    wbase2 + msk * (woff + o * 128));
                const f32x4 u = __builtin_amdgcn_mfma_f32_16x16x32_bf16(
                                    wf, xf, (f32x4){0.f,0.f,0.f,0.f}, 0, 0, 0);
                sacc[o] += u * (elg[o] * rden);
            }
        } else {
            #pragma unroll
            for (int o = 0; o < OO; ++o) {
                const short8 wf = *reinterpret_cast<const short8*>(
                    wbase + msk * (woff + o * 128));
                const f32x4 u = __builtin_amdgcn_mfma_f32_16x16x32_bf16(
                                    wf, xf, (f32x4){0.f,0.f,0.f,0.f}, 0, 0, 0);
                sacc[o] += u;
            }
        }
    }

    // direct float4 stores: 4 q-groups fill each 64B line (r12-verified)
    {
        const float mul = first ? 0.1f : 1.0f;   // uniform c=0.1 folded here
        float* sp = s_part + (((size_t)blockIdx.x * BATCH + b) * OO) * EE + 4 * q;
        #pragma unroll
        for (int o = 0; o < OO; ++o) {
            const f32x4 t = sacc[o];
            float4 w4;
            w4.x = mul * t[0]; w4.y = mul * t[1];
            w4.z = mul * t[2]; w4.w = mul * t[3];
            *reinterpret_cast<float4*>(sp + o * EE) = w4;
        }
    }
}

// squash: 1024 threads, 16-way chunk split (18 strided loads/thread all in
// flight) + LDS tree; wave 0 squashes + stores.
__global__ __launch_bounds__(1024) void caps_squash_kernel(
    const float* __restrict__ s_part,  // [NCHUNK][256][10][16]
    float* __restrict__ V,             // [256][10][16]
    float* __restrict__ out,           // [256][10][16]
    int accum, int last)
{
    __shared__ float red[15][64];
    const int lane = threadIdx.x & 63;
    const int w    = threadIdx.x >> 6;          // 0..15
    const int g    = blockIdx.x * 64 + lane;    // < 40960

    const float* sp = s_part + g;
    float s = 0.f;
    #pragma unroll
    for (int i = 0; i < NCHUNK / 16; ++i)       // 18 loads, all outstanding
        s += sp[(size_t)(w * (NCHUNK / 16) + i) * (BATCH * OO * EE)];

    if (w > 0) red[w - 1][lane] = s;
    __syncthreads();
    if (w == 0) {
        #pragma unroll
        for (int i = 0; i < 15; ++i) s += red[i][lane];

        // squared norm over the 16-element e axis (lanes g..g+15 share (b,o))
        float sq = s * s;
        #pragma unroll
        for (int m = 1; m < 16; m <<= 1) sq += __shfl_xor(sq, m, 16);

        const float scale = sq / (1.f + sq) / (sqrtf(sq) + 1e-6f);
        const float v = scale * s;

        if (last)       out[g] = v;
        else if (accum) V[g]  += v;
        else            V[g]   = v;
    }
}

extern "C" void kernel_launch(void* const* d_in, const int* in_sizes, int n_in,
                              void* d_out, int out_size, void* d_ws, size_t ws_size,
                              hipStream_t stream) {
    const float* x = (const float*)d_in[0];   // [256,32,6,6,8]
    const float* W = (const float*)d_in[1];   // [1,32,6,6,10,8,16]
    float* out = (float*)d_out;               // [256,10,16]

    float* s_part = (float*)d_ws;                                   // 288*40960 floats
    float* V      = s_part + (size_t)NCHUNK * BATCH * OO * EE;      // 40960 floats
    unsigned short* w_hi = (unsigned short*)(V + BATCH * OO * EE);
    unsigned short* w_lo = w_hi + WHALF;
    // ws use ~53 MB << 268 MB

    dim3 grid(NCHUNK, NBT), blk(NT);
    const int sq_blocks = (BATCH * OO * EE) / 64;   // 640

    // one-time W conversion into MFMA feed layout (~5us)
    caps_prep_kernel<<<(IC * 160) / 256, 256, 0, stream>>>(W, w_hi, w_lo);

    // iteration 1: b=0 -> c uniform 0.1; v1 -> V
    caps_pass_kernel<<<grid, blk, 0, stream>>>(x, w_hi, w_lo, V, s_part, 1);
    caps_squash_kernel<<<sq_blocks, 1024, 0, stream>>>(s_part, V, out, 0, 0);
    // iteration 2: logits = dot(u_hat, v1); V += v2
    caps_pass_kernel<<<grid, blk, 0, stream>>>(x, w_hi, w_lo, V, s_part, 0);
    caps_squash_kernel<<<sq_blocks, 1024, 0, stream>>>(s_part, V, out, 1, 0);
    // iteration 3 (final): logits = dot(u_hat, v1+v2); output v3
    caps_pass_kernel<<<grid, blk, 0, stream>>>(x, w_hi, w_lo, V, s_part, 0);
    caps_squash_kernel<<<sq_blocks, 1024, 0, stream>>>(s_part, V, out, 0, 1);
}